// Round 14
// baseline (411.182 us; speedup 1.0000x reference)
//
#include <hip/hip_runtime.h>

// VQ-VAE VectorQuantizer: z_e [32,1024,256] f32, codebook [8192,256] f32.
// Outputs (flat f32): z_q_st [8388608], vq_loss [1], codes_idx-as-float [32768].
//
// Verified semantics (r3-r8 passing): ref = fp32 numpy; dist=(z_sq-2*ze)+e_sq
// quantized at ulp(~256)~1.5e-5, ties -> first index. Scan = bf16 MFMA dot;
// within-margin candidates re-scored exactly (fp64 dot -> fp32, np-pairwise
// z_sq/e_sq, packed (bits,idx) min, first index).
//
// r9-r12 (code-split frame) failed deterministically and resisted bisection
// -> frame abandoned. r13 = hybrid of two PASSING kernels only: r7's
// 32-rows-per-wave scan shape + r8's 64-row block & staging/sync. 2 waves
// per block (halves LDS read amplification vs r8 = the measured bottleneck).
// Rows-split (every wave scans ALL codes), block-LDS tiles from pbz via
// global_load_lds, 1 full-drain barrier/chunk, margin/CLIST r7-verified.

#define NUM_CODES 8192
#define DIM 256
#define TOTAL_ROWS 32768
#define ROWS_PER_BLOCK 64
#define TILE_K 32
#define NCHUNK (NUM_CODES / TILE_K)     // 256
#define OUT_LOSS_OFF 8388608
#define OUT_IDX_OFF 8388609
#define LOSS_SCALE (1.25 / 8388608.0)   // (1+BETA)/(B*N*D)
#define DOT_MARGIN 3.5e-4f              // r7/r8-verified
#define CLIST_MAX 160                   // r7-verified for 32 rows/wave

typedef __attribute__((ext_vector_type(8))) short bf16x8;
typedef __attribute__((ext_vector_type(4))) float f32x4;

#define AS1 __attribute__((address_space(1)))
#define AS3 __attribute__((address_space(3)))
static __device__ __forceinline__ void gload_lds16(const void* g, void* l) {
    __builtin_amdgcn_global_load_lds((const AS1 unsigned int*)(uintptr_t)g,
                                     (AS3 unsigned int*)(uintptr_t)l, 16, 0, 0);
}

static __device__ __forceinline__ unsigned short f2bf(float f) {   // RNE
    union { float f; unsigned u; } v; v.f = f;
    return (unsigned short)((v.u + 0x7FFF + ((v.u >> 16) & 1)) >> 16);
}

static __device__ __forceinline__ float sq32(float v) {  // block contraction
    float s = v * v;
    asm("" : "+v"(s));
    return s;
}

// numpy pairwise sum of 256 fp32 squares, 16 lanes/row (verified r3-r8).
static __device__ __forceinline__ float pairwise256_sq(
        const float* __restrict__ base, int l) {
    const int h = (l >> 3) & 1, j = l & 7;
    const float* p = base + h * 128 + j;
    float acc = sq32(p[0]);
    #pragma unroll
    for (int m = 1; m < 16; ++m) acc += sq32(p[m * 8]);
    acc += __shfl_xor(acc, 1);
    acc += __shfl_xor(acc, 2);
    acc += __shfl_xor(acc, 4);
    acc += __shfl_xor(acc, 8);
    return acc;
}

// ---------------------------------------------- row ||x||^2 (np pairwise) ----
__global__ __launch_bounds__(64) void rowsq_kernel(const float* __restrict__ x,
                                                   float* __restrict__ sq) {
    const int l = threadIdx.x;
    const long row = ((long)blockIdx.x << 2) + (l >> 4);
    float s = pairwise256_sq(x + row * DIM, l);
    if ((l & 15) == 0) sq[row] = s;
}

// ---- fp32 -> bf16, pre-swizzled chunk-major staging image (r5-r8) ---------
// pbz[ch*1024 + idx] (16B slot): code c = idx>>5 (in chunk), sw = idx&31,
// source slot s = sw ^ (c&7)  => identical LDS image to r7/r8 verified layout.
__global__ __launch_bounds__(256) void cvt_swz_kernel(
        const float* __restrict__ cb, uint4* __restrict__ pbz) {
    const int o = blockIdx.x * 256 + threadIdx.x;    // slot 0..262143
    const int ch = o >> 10, idx = o & 1023;
    const int c = idx >> 5, sw = idx & 31;
    const int s = sw ^ (c & 7);
    const float* p = cb + ((long)(ch * TILE_K + c) << 8) + s * 8;
    float4 a = *(const float4*)p, b = *(const float4*)(p + 4);
    union { unsigned short us[8]; uint4 v; } r;
    r.us[0] = f2bf(a.x); r.us[1] = f2bf(a.y); r.us[2] = f2bf(a.z); r.us[3] = f2bf(a.w);
    r.us[4] = f2bf(b.x); r.us[5] = f2bf(b.y); r.us[6] = f2bf(b.z); r.us[7] = f2bf(b.w);
    pbz[o] = r.v;
}

// ------------------------------------------------ MFMA scan + refine ----
__global__ __launch_bounds__(128, 2) void vq_scan_kernel(
        const float* __restrict__ z, const float* __restrict__ cb,
        const uint4* __restrict__ pbz, const float* __restrict__ esq,
        float* __restrict__ out, double* __restrict__ loss_acc) {
    __shared__ bf16x8 ct[2][TILE_K * 32];            // 2 x 16 KB
    __shared__ unsigned long long winner[ROWS_PER_BLOCK];
    __shared__ float zsql[ROWS_PER_BLOCK];
    __shared__ unsigned clist[2][CLIST_MAX];
    __shared__ int ccnt[2];

    const int tid = threadIdx.x;                     // 0..127 (2 waves)
    const int w = tid >> 6, l = tid & 63;
    const int cl = l & 15, g = l >> 4;
    const int x7 = cl & 7;
    const long rowbase = (long)blockIdx.x * ROWS_PER_BLOCK;
    const int wrowL = w * 32;                        // wave owns 32 rows

    // wave-private init only
    if (l < 32) winner[wrowL + l] = ~0ull;
    if (l == 0) ccnt[w] = 0;

    // stage: 8 x 16B per thread per chunk; linear copy (pre-swizzled source).
    // LDS dest per (round i, wave w) is wave-uniform; lane auto-offsets by 16B.
    #define STAGE(ch_, buf_) { \
        const char* gs_ = (const char*)pbz + ((long)(ch_) << 14) + (w << 10) + (l << 4); \
        char* ld_ = (char*)&ct[buf_][0] + (w << 10); \
        _Pragma("unroll") \
        for (int i_ = 0; i_ < 8; ++i_) \
            gload_lds16(gs_ + i_ * 2048, ld_ + i_ * 2048); \
    }

    STAGE(0, 0);                                     // lands under setup below

    // ---- A-frags: wave's 32 z rows (2 M-tiles), whole K=256, in regs ----
    bf16x8 af[2][8];
    #pragma unroll
    for (int t = 0; t < 2; ++t) {
        const long r = rowbase + wrowL + t * 16 + cl;
        #pragma unroll
        for (int ks = 0; ks < 8; ++ks) {
            const float* p = z + r * DIM + ks * 32 + g * 8;
            float4 a = *(const float4*)p, b = *(const float4*)(p + 4);
            bf16x8 v;
            v[0] = f2bf(a.x); v[1] = f2bf(a.y); v[2] = f2bf(a.z); v[3] = f2bf(a.w);
            v[4] = f2bf(b.x); v[5] = f2bf(b.y); v[6] = f2bf(b.z); v[7] = f2bf(b.w);
            af[t][ks] = v;
        }
    }
    // ---- z_sq for wave's 32 rows (np-pairwise, bit-exact), 4 rows/call ----
    #pragma unroll
    for (int p4 = 0; p4 < 8; ++p4) {
        const int r0 = wrowL + p4 * 4 + (l >> 4);
        float s = pairwise256_sq(z + (rowbase + r0) * DIM, l);
        if ((l & 15) == 0) zsql[r0] = s;
    }
    __syncthreads();

    // per-(lane,row-slot) top-3 packed keys: monotone(dot) | code(13 LSB)
    unsigned k1a[8], k2a[8], k3a[8];
    #pragma unroll
    for (int i = 0; i < 8; ++i) { k1a[i] = 0u; k2a[i] = 0u; k3a[i] = 0u; }

    // r7/r8-verified top-3 insert (pure C compare chain)
    #define INSERT(rs_, sv_, kc_) { \
        unsigned u_ = __float_as_uint(sv_); \
        u_ ^= ((unsigned)((int)u_ >> 31)) | 0x80000000u; \
        u_ = (u_ & 0xFFFFE000u) | (kc_); \
        unsigned mx_ = k1a[rs_] > u_ ? k1a[rs_] : u_; \
        unsigned mn_ = k1a[rs_] > u_ ? u_ : k1a[rs_]; \
        k1a[rs_] = mx_; \
        unsigned mx2_ = k2a[rs_] > mn_ ? k2a[rs_] : mn_; \
        unsigned mn2_ = k2a[rs_] > mn_ ? mn_ : k2a[rs_]; \
        k2a[rs_] = mx2_; \
        k3a[rs_] = k3a[rs_] > mn2_ ? k3a[rs_] : mn2_; \
    }

    for (int ch = 0; ch < NCHUNK; ++ch) {
        const int buf = ch & 1;
        if (ch + 1 < NCHUNK) STAGE(ch + 1, buf ^ 1);

        bf16x8 breg[16];                         // all B-frags up-front
        #pragma unroll
        for (int ks = 0; ks < 8; ++ks)
            #pragma unroll
            for (int nt = 0; nt < 2; ++nt)
                breg[ks * 2 + nt] =
                    ct[buf][nt * 512 + cl * 32 + (((ks << 2) + g) ^ x7)];

        f32x4 acc[2][2];
        #pragma unroll
        for (int t = 0; t < 2; ++t)
            #pragma unroll
            for (int n = 0; n < 2; ++n) acc[t][n] = (f32x4){0.f, 0.f, 0.f, 0.f};
        #pragma unroll
        for (int ks = 0; ks < 8; ++ks) {
            #pragma unroll
            for (int nt = 0; nt < 2; ++nt) {
                acc[0][nt] = __builtin_amdgcn_mfma_f32_16x16x32_bf16(
                    af[0][ks], breg[ks * 2 + nt], acc[0][nt], 0, 0, 0);
                acc[1][nt] = __builtin_amdgcn_mfma_f32_16x16x32_bf16(
                    af[1][ks], breg[ks * 2 + nt], acc[1][nt], 0, 0, 0);
            }
        }

        const unsigned kc0 = (unsigned)(ch * TILE_K + cl);
        #pragma unroll
        for (int t = 0; t < 2; ++t)
            #pragma unroll
            for (int nt = 0; nt < 2; ++nt)
                #pragma unroll
                for (int r = 0; r < 4; ++r)
                    INSERT(t * 4 + r, acc[t][nt][r], nt ? (kc0 + 16) : kc0);

        __syncthreads();   // drains gll (vmcnt) + releases buf for ch+2
    }

    // ---- collect within-margin candidates (per-row max threshold) ----
    #define COLLECT(rs_, T_, R_) { \
        unsigned gm_ = k1a[rs_]; \
        unsigned t_; \
        t_ = __shfl_xor(gm_, 1); gm_ = gm_ > t_ ? gm_ : t_; \
        t_ = __shfl_xor(gm_, 2); gm_ = gm_ > t_ ? gm_ : t_; \
        t_ = __shfl_xor(gm_, 4); gm_ = gm_ > t_ ? gm_ : t_; \
        t_ = __shfl_xor(gm_, 8); gm_ = gm_ > t_ ? gm_ : t_; \
        unsigned sb_ = (gm_ & 0x80000000u) ? (gm_ ^ 0x80000000u) : ~gm_; \
        float gs_ = __uint_as_float(sb_) - DOT_MARGIN; \
        unsigned tu_ = __float_as_uint(gs_); \
        tu_ ^= ((unsigned)((int)tu_ >> 31)) | 0x80000000u; \
        tu_ &= 0xFFFFE000u; \
        const unsigned rowp_ = (unsigned)(wrowL + T_ * 16 + g * 4 + R_) << 16; \
        if (k1a[rs_] >= tu_) { int p_ = atomicAdd(&ccnt[w], 1); \
            if (p_ < CLIST_MAX) clist[w][p_] = rowp_ | (k1a[rs_] & 0x1FFFu); } \
        if (k2a[rs_] >= tu_) { int p_ = atomicAdd(&ccnt[w], 1); \
            if (p_ < CLIST_MAX) clist[w][p_] = rowp_ | (k2a[rs_] & 0x1FFFu); } \
        if (k3a[rs_] >= tu_) { int p_ = atomicAdd(&ccnt[w], 1); \
            if (p_ < CLIST_MAX) clist[w][p_] = rowp_ | (k3a[rs_] & 0x1FFFu); } \
    }
    COLLECT(0, 0, 0); COLLECT(1, 0, 1); COLLECT(2, 0, 2); COLLECT(3, 0, 3);
    COLLECT(4, 1, 0); COLLECT(5, 1, 1); COLLECT(6, 1, 2); COLLECT(7, 1, 3);
    __syncthreads();

    // ---- exact refine (verified r3 formula); wave-owned rows only ----
    const int n = ccnt[w] < CLIST_MAX ? ccnt[w] : CLIST_MAX;
    for (int j = 0; j < n; ++j) {
        const unsigned e = clist[w][j];
        const int rowL = e >> 16;                    // in wave's own 32 rows
        const int code = e & 0x1FFF;
        const long grow = rowbase + rowL;
        float4 zz = *(const float4*)(z + grow * DIM + l * 4);
        float4 cc = *(const float4*)(cb + (long)code * DIM + l * 4);
        double dd = (double)zz.x * cc.x + (double)zz.y * cc.y
                  + (double)zz.z * cc.z + (double)zz.w * cc.w;
        dd += __shfl_xor(dd, 1);
        dd += __shfl_xor(dd, 2);
        dd += __shfl_xor(dd, 4);
        dd += __shfl_xor(dd, 8);
        dd += __shfl_xor(dd, 16);
        dd += __shfl_xor(dd, 32);
        const float s = (zsql[rowL] - 2.0f * (float)dd) + esq[code];
        if (l == 0) {
            const unsigned long long p =
                ((unsigned long long)__float_as_uint(s) << 32) | (unsigned)code;
            if (p < winner[rowL]) winner[rowL] = p;  // rows wave-exclusive
        }
    }
    __syncthreads();

    // ---- epilogue (r7/r8-verified): wave w writes rows wrowL..wrowL+31 ----
    double lacc = 0.0;
    #pragma unroll 1
    for (int i = 0; i < 32; ++i) {
        const int rowL = wrowL + i;
        const long grow = rowbase + rowL;
        const int kw = (int)(winner[rowL] & 0x1FFFull);
        float4 zz = *(const float4*)(z + grow * DIM + l * 4);
        float4 cq = *(const float4*)(cb + (long)kw * DIM + l * 4);
        float4 oo;
        oo.x = zz.x + (cq.x - zz.x); oo.y = zz.y + (cq.y - zz.y);
        oo.z = zz.z + (cq.z - zz.z); oo.w = zz.w + (cq.w - zz.w);
        *(float4*)(out + grow * DIM + l * 4) = oo;
        if (l == 0) out[OUT_IDX_OFF + grow] = (float)kw;
        const double d0 = (double)cq.x - zz.x, d1 = (double)cq.y - zz.y;
        const double d2 = (double)cq.z - zz.z, d3 = (double)cq.w - zz.w;
        lacc += d0 * d0 + d1 * d1 + d2 * d2 + d3 * d3;
    }
    lacc += __shfl_xor(lacc, 1);
    lacc += __shfl_xor(lacc, 2);
    lacc += __shfl_xor(lacc, 4);
    lacc += __shfl_xor(lacc, 8);
    lacc += __shfl_xor(lacc, 16);
    lacc += __shfl_xor(lacc, 32);
    if (l == 0) atomicAdd(loss_acc, lacc);
}

// ------------------------------------------------------------ finalize ----
__global__ void vq_finalize_kernel(const double* __restrict__ loss_acc,
                                   float* __restrict__ out) {
    out[OUT_LOSS_OFF] = (float)(*loss_acc * LOSS_SCALE);
}

// -------------------------------------------------------------- launch ----
extern "C" void kernel_launch(void* const* d_in, const int* in_sizes, int n_in,
                              void* d_out, int out_size, void* d_ws, size_t ws_size,
                              hipStream_t stream) {
    const float* z  = (const float*)d_in[0];
    const float* cb = (const float*)d_in[1];
    float* out = (float*)d_out;
    double* loss_acc = (double*)d_ws;                              // 8 B
    float* esq = (float*)((char*)d_ws + 4096);                     // 32 KB
    uint4* pbz = (uint4*)((char*)d_ws + 262144);                   // 4 MB image

    hipMemsetAsync(d_ws, 0, 8, stream);
    rowsq_kernel<<<NUM_CODES / 4, 64, 0, stream>>>(cb, esq);
    cvt_swz_kernel<<<NUM_CODES * TILE_K / 256, 256, 0, stream>>>(cb, pbz);
    vq_scan_kernel<<<TOTAL_ROWS / ROWS_PER_BLOCK, 128, 0, stream>>>(
        z, cb, pbz, esq, out, loss_acc);
    vq_finalize_kernel<<<1, 1, 0, stream>>>(loss_acc, out);
}

// Round 15
// 354.247 us; speedup vs baseline: 1.1607x; 1.1607x over previous
//
#include <hip/hip_runtime.h>

// VQ-VAE VectorQuantizer: z_e [32,1024,256] f32, codebook [8192,256] f32.
// Outputs (flat f32): z_q_st [8388608], vq_loss [1], codes_idx-as-float [32768].
//
// Verified semantics (r3-r8, r14 passing): ref = fp32 numpy; dist =
// (z_sq-2*ze)+e_sq quantized at ulp(~256)~1.5e-5, ties -> first index.
// Scan = bf16 MFMA dot; within-margin candidates re-scored exactly (fp64
// dot -> fp32, np-pairwise z_sq/e_sq, packed (bits,idx) min, first index).
//
// r14 verified the 2-wave/32-rows-per-wave scan but was GRID-limited
// (512x128thr = 1 wave/SIMD, latency-bound). THIS ROUND: code-half split at
// BLOCK level -> grid 1024 (4 blocks/CU, 2 waves/SIMD). Each block scans its
// 4096-code half (margin vs half-max is provably a superset: the exact argmin
// is within margin of its own half's max). Exact refine in-block, global
// winner merge via atomicMin(u64) packed keys (order-independent, first-index
// exact). Separate epilogue kernel (r8 pattern) writes outputs from winners.

#define NUM_CODES 8192
#define DIM 256
#define TOTAL_ROWS 32768
#define ROWS_PER_BLOCK 64
#define TILE_K 32
#define NCHUNK_HALF 128                 // chunks per code-half
#define OUT_LOSS_OFF 8388608
#define OUT_IDX_OFF 8388609
#define LOSS_SCALE (1.25 / 8388608.0)   // (1+BETA)/(B*N*D)
#define DOT_MARGIN 3.5e-4f              // r7/r8/r14-verified
#define CLIST_MAX 160

typedef __attribute__((ext_vector_type(8))) short bf16x8;
typedef __attribute__((ext_vector_type(4))) float f32x4;

#define AS1 __attribute__((address_space(1)))
#define AS3 __attribute__((address_space(3)))
static __device__ __forceinline__ void gload_lds16(const void* g, void* l) {
    __builtin_amdgcn_global_load_lds((const AS1 unsigned int*)(uintptr_t)g,
                                     (AS3 unsigned int*)(uintptr_t)l, 16, 0, 0);
}

static __device__ __forceinline__ unsigned short f2bf(float f) {   // RNE
    union { float f; unsigned u; } v; v.f = f;
    return (unsigned short)((v.u + 0x7FFF + ((v.u >> 16) & 1)) >> 16);
}

static __device__ __forceinline__ float sq32(float v) {  // block contraction
    float s = v * v;
    asm("" : "+v"(s));
    return s;
}

// numpy pairwise sum of 256 fp32 squares, 16 lanes/row (verified r3-r14).
static __device__ __forceinline__ float pairwise256_sq(
        const float* __restrict__ base, int l) {
    const int h = (l >> 3) & 1, j = l & 7;
    const float* p = base + h * 128 + j;
    float acc = sq32(p[0]);
    #pragma unroll
    for (int m = 1; m < 16; ++m) acc += sq32(p[m * 8]);
    acc += __shfl_xor(acc, 1);
    acc += __shfl_xor(acc, 2);
    acc += __shfl_xor(acc, 4);
    acc += __shfl_xor(acc, 8);
    return acc;
}

// ---------------------------------------------- row ||x||^2 (np pairwise) ----
__global__ __launch_bounds__(64) void rowsq_kernel(const float* __restrict__ x,
                                                   float* __restrict__ sq) {
    const int l = threadIdx.x;
    const long row = ((long)blockIdx.x << 2) + (l >> 4);
    float s = pairwise256_sq(x + row * DIM, l);
    if ((l & 15) == 0) sq[row] = s;
}

// ---- fp32 -> bf16, pre-swizzled chunk-major staging image (r5-r14) --------
__global__ __launch_bounds__(256) void cvt_swz_kernel(
        const float* __restrict__ cb, uint4* __restrict__ pbz) {
    const int o = blockIdx.x * 256 + threadIdx.x;    // slot 0..262143
    const int ch = o >> 10, idx = o & 1023;
    const int c = idx >> 5, sw = idx & 31;
    const int s = sw ^ (c & 7);
    const float* p = cb + ((long)(ch * TILE_K + c) << 8) + s * 8;
    float4 a = *(const float4*)p, b = *(const float4*)(p + 4);
    union { unsigned short us[8]; uint4 v; } r;
    r.us[0] = f2bf(a.x); r.us[1] = f2bf(a.y); r.us[2] = f2bf(a.z); r.us[3] = f2bf(a.w);
    r.us[4] = f2bf(b.x); r.us[5] = f2bf(b.y); r.us[6] = f2bf(b.z); r.us[7] = f2bf(b.w);
    pbz[o] = r.v;
}

// ------------------------------------------------ MFMA scan + refine ----
// grid 1024: bid&511 = row-block, bid>>9 = code-half. Scan internals are the
// r14-VERIFIED code; only the chunk offset, code labels, and the global
// atomicMin winner merge are new.
__global__ __launch_bounds__(128, 2) void vq_scan_kernel(
        const float* __restrict__ z, const float* __restrict__ cb,
        const uint4* __restrict__ pbz, const float* __restrict__ esq,
        unsigned long long* __restrict__ gwin) {
    __shared__ bf16x8 ct[2][TILE_K * 32];            // 2 x 16 KB
    __shared__ float zsql[ROWS_PER_BLOCK];
    __shared__ unsigned clist[2][CLIST_MAX];
    __shared__ int ccnt[2];

    const int tid = threadIdx.x;                     // 0..127 (2 waves)
    const int w = tid >> 6, l = tid & 63;
    const int cl = l & 15, g = l >> 4;
    const int x7 = cl & 7;
    const int rowblk = blockIdx.x & 511;
    const int half = blockIdx.x >> 9;
    const int ch0 = half * NCHUNK_HALF;              // first global chunk
    const long rowbase = (long)rowblk * ROWS_PER_BLOCK;
    const int wrowL = w * 32;                        // wave owns 32 rows

    if (l == 0) ccnt[w] = 0;

    #define STAGE(gch_, buf_) { \
        const char* gs_ = (const char*)pbz + ((long)(gch_) << 14) + (w << 10) + (l << 4); \
        char* ld_ = (char*)&ct[buf_][0] + (w << 10); \
        _Pragma("unroll") \
        for (int i_ = 0; i_ < 8; ++i_) \
            gload_lds16(gs_ + i_ * 2048, ld_ + i_ * 2048); \
    }

    STAGE(ch0, 0);                                   // lands under setup below

    // ---- A-frags: wave's 32 z rows (2 M-tiles), whole K=256, in regs ----
    bf16x8 af[2][8];
    #pragma unroll
    for (int t = 0; t < 2; ++t) {
        const long r = rowbase + wrowL + t * 16 + cl;
        #pragma unroll
        for (int ks = 0; ks < 8; ++ks) {
            const float* p = z + r * DIM + ks * 32 + g * 8;
            float4 a = *(const float4*)p, b = *(const float4*)(p + 4);
            bf16x8 v;
            v[0] = f2bf(a.x); v[1] = f2bf(a.y); v[2] = f2bf(a.z); v[3] = f2bf(a.w);
            v[4] = f2bf(b.x); v[5] = f2bf(b.y); v[6] = f2bf(b.z); v[7] = f2bf(b.w);
            af[t][ks] = v;
        }
    }
    // ---- z_sq for wave's 32 rows (np-pairwise, bit-exact), 4 rows/call ----
    #pragma unroll
    for (int p4 = 0; p4 < 8; ++p4) {
        const int r0 = wrowL + p4 * 4 + (l >> 4);
        float s = pairwise256_sq(z + (rowbase + r0) * DIM, l);
        if ((l & 15) == 0) zsql[r0] = s;
    }
    __syncthreads();

    // per-(lane,row-slot) top-3 packed keys: monotone(dot) | code(13 LSB)
    unsigned k1a[8], k2a[8], k3a[8];
    #pragma unroll
    for (int i = 0; i < 8; ++i) { k1a[i] = 0u; k2a[i] = 0u; k3a[i] = 0u; }

    // r7/r8/r14-verified top-3 insert (pure C compare chain)
    #define INSERT(rs_, sv_, kc_) { \
        unsigned u_ = __float_as_uint(sv_); \
        u_ ^= ((unsigned)((int)u_ >> 31)) | 0x80000000u; \
        u_ = (u_ & 0xFFFFE000u) | (kc_); \
        unsigned mx_ = k1a[rs_] > u_ ? k1a[rs_] : u_; \
        unsigned mn_ = k1a[rs_] > u_ ? u_ : k1a[rs_]; \
        k1a[rs_] = mx_; \
        unsigned mx2_ = k2a[rs_] > mn_ ? k2a[rs_] : mn_; \
        unsigned mn2_ = k2a[rs_] > mn_ ? mn_ : k2a[rs_]; \
        k2a[rs_] = mx2_; \
        k3a[rs_] = k3a[rs_] > mn2_ ? k3a[rs_] : mn2_; \
    }

    for (int ch = 0; ch < NCHUNK_HALF; ++ch) {
        const int buf = ch & 1;
        if (ch + 1 < NCHUNK_HALF) STAGE(ch0 + ch + 1, buf ^ 1);

        bf16x8 breg[16];                         // all B-frags up-front
        #pragma unroll
        for (int ks = 0; ks < 8; ++ks)
            #pragma unroll
            for (int nt = 0; nt < 2; ++nt)
                breg[ks * 2 + nt] =
                    ct[buf][nt * 512 + cl * 32 + (((ks << 2) + g) ^ x7)];

        f32x4 acc[2][2];
        #pragma unroll
        for (int t = 0; t < 2; ++t)
            #pragma unroll
            for (int n = 0; n < 2; ++n) acc[t][n] = (f32x4){0.f, 0.f, 0.f, 0.f};
        #pragma unroll
        for (int ks = 0; ks < 8; ++ks) {
            #pragma unroll
            for (int nt = 0; nt < 2; ++nt) {
                acc[0][nt] = __builtin_amdgcn_mfma_f32_16x16x32_bf16(
                    af[0][ks], breg[ks * 2 + nt], acc[0][nt], 0, 0, 0);
                acc[1][nt] = __builtin_amdgcn_mfma_f32_16x16x32_bf16(
                    af[1][ks], breg[ks * 2 + nt], acc[1][nt], 0, 0, 0);
            }
        }

        const unsigned kc0 = (unsigned)((ch0 + ch) * TILE_K + cl);
        #pragma unroll
        for (int t = 0; t < 2; ++t)
            #pragma unroll
            for (int nt = 0; nt < 2; ++nt)
                #pragma unroll
                for (int r = 0; r < 4; ++r)
                    INSERT(t * 4 + r, acc[t][nt][r], nt ? (kc0 + 16) : kc0);

        __syncthreads();   // drains gll (vmcnt) + releases buf for ch+2
    }

    // ---- collect within-margin candidates (per-row max over this half) ----
    #define COLLECT(rs_, T_, R_) { \
        unsigned gm_ = k1a[rs_]; \
        unsigned t_; \
        t_ = __shfl_xor(gm_, 1); gm_ = gm_ > t_ ? gm_ : t_; \
        t_ = __shfl_xor(gm_, 2); gm_ = gm_ > t_ ? gm_ : t_; \
        t_ = __shfl_xor(gm_, 4); gm_ = gm_ > t_ ? gm_ : t_; \
        t_ = __shfl_xor(gm_, 8); gm_ = gm_ > t_ ? gm_ : t_; \
        unsigned sb_ = (gm_ & 0x80000000u) ? (gm_ ^ 0x80000000u) : ~gm_; \
        float gs_ = __uint_as_float(sb_) - DOT_MARGIN; \
        unsigned tu_ = __float_as_uint(gs_); \
        tu_ ^= ((unsigned)((int)tu_ >> 31)) | 0x80000000u; \
        tu_ &= 0xFFFFE000u; \
        const unsigned rowp_ = (unsigned)(wrowL + T_ * 16 + g * 4 + R_) << 16; \
        if (k1a[rs_] >= tu_) { int p_ = atomicAdd(&ccnt[w], 1); \
            if (p_ < CLIST_MAX) clist[w][p_] = rowp_ | (k1a[rs_] & 0x1FFFu); } \
        if (k2a[rs_] >= tu_) { int p_ = atomicAdd(&ccnt[w], 1); \
            if (p_ < CLIST_MAX) clist[w][p_] = rowp_ | (k2a[rs_] & 0x1FFFu); } \
        if (k3a[rs_] >= tu_) { int p_ = atomicAdd(&ccnt[w], 1); \
            if (p_ < CLIST_MAX) clist[w][p_] = rowp_ | (k3a[rs_] & 0x1FFFu); } \
    }
    COLLECT(0, 0, 0); COLLECT(1, 0, 1); COLLECT(2, 0, 2); COLLECT(3, 0, 3);
    COLLECT(4, 1, 0); COLLECT(5, 1, 1); COLLECT(6, 1, 2); COLLECT(7, 1, 3);

    // ---- exact refine (verified r3 formula); global first-index merge ----
    // (clist/ccnt/zsql are wave-private: no barrier needed)
    const int n = ccnt[w] < CLIST_MAX ? ccnt[w] : CLIST_MAX;
    for (int j = 0; j < n; ++j) {
        const unsigned e = clist[w][j];
        const int rowL = e >> 16;                    // in wave's own 32 rows
        const int code = e & 0x1FFF;
        const long grow = rowbase + rowL;
        float4 zz = *(const float4*)(z + grow * DIM + l * 4);
        float4 cc = *(const float4*)(cb + (long)code * DIM + l * 4);
        double dd = (double)zz.x * cc.x + (double)zz.y * cc.y
                  + (double)zz.z * cc.z + (double)zz.w * cc.w;
        dd += __shfl_xor(dd, 1);
        dd += __shfl_xor(dd, 2);
        dd += __shfl_xor(dd, 4);
        dd += __shfl_xor(dd, 8);
        dd += __shfl_xor(dd, 16);
        dd += __shfl_xor(dd, 32);
        const float s = (zsql[rowL] - 2.0f * (float)dd) + esq[code];
        if (l == 0) {
            const unsigned long long p =
                ((unsigned long long)__float_as_uint(s) << 32) | (unsigned)code;
            atomicMin(&gwin[grow], p);               // device-scope, exact
        }
    }
}

// ---- epilogue (r8-verified pattern): outputs from final winners ----------
__global__ __launch_bounds__(256) void vq_out_kernel(
        const float* __restrict__ z, const float* __restrict__ cb,
        const unsigned long long* __restrict__ gwin,
        float* __restrict__ out, double* __restrict__ loss_acc) {
    const int tid = threadIdx.x;
    const int w = tid >> 6, l = tid & 63;
    const long rowbase = (long)blockIdx.x * ROWS_PER_BLOCK;
    double lacc = 0.0;
    #pragma unroll 1
    for (int i = 0; i < 16; ++i) {
        const long grow = rowbase + w * 16 + i;
        const int kw = (int)(gwin[grow] & 0x1FFFull);
        float4 zz = *(const float4*)(z + grow * DIM + l * 4);
        float4 cq = *(const float4*)(cb + (long)kw * DIM + l * 4);
        float4 oo;
        oo.x = zz.x + (cq.x - zz.x); oo.y = zz.y + (cq.y - zz.y);
        oo.z = zz.z + (cq.z - zz.z); oo.w = zz.w + (cq.w - zz.w);
        *(float4*)(out + grow * DIM + l * 4) = oo;
        if (l == 0) out[OUT_IDX_OFF + grow] = (float)kw;
        const double d0 = (double)cq.x - zz.x, d1 = (double)cq.y - zz.y;
        const double d2 = (double)cq.z - zz.z, d3 = (double)cq.w - zz.w;
        lacc += d0 * d0 + d1 * d1 + d2 * d2 + d3 * d3;
    }
    lacc += __shfl_xor(lacc, 1);
    lacc += __shfl_xor(lacc, 2);
    lacc += __shfl_xor(lacc, 4);
    lacc += __shfl_xor(lacc, 8);
    lacc += __shfl_xor(lacc, 16);
    lacc += __shfl_xor(lacc, 32);
    if (l == 0) atomicAdd(loss_acc, lacc);
}

// ------------------------------------------------------------ finalize ----
__global__ void vq_finalize_kernel(const double* __restrict__ loss_acc,
                                   float* __restrict__ out) {
    out[OUT_LOSS_OFF] = (float)(*loss_acc * LOSS_SCALE);
}

// -------------------------------------------------------------- launch ----
extern "C" void kernel_launch(void* const* d_in, const int* in_sizes, int n_in,
                              void* d_out, int out_size, void* d_ws, size_t ws_size,
                              hipStream_t stream) {
    const float* z  = (const float*)d_in[0];
    const float* cb = (const float*)d_in[1];
    float* out = (float*)d_out;
    double* loss_acc = (double*)d_ws;                                  // 8 B
    float* esq = (float*)((char*)d_ws + 1024);                         // 32 KB
    unsigned long long* gwin =
        (unsigned long long*)((char*)d_ws + 65536);                    // 256 KB
    uint4* pbz = (uint4*)((char*)d_ws + 393216);                       // 4 MB

    hipMemsetAsync(d_ws, 0, 8, stream);                  // loss accumulator
    hipMemsetAsync(gwin, 0xFF, TOTAL_ROWS * 8, stream);  // winners = ~0
    rowsq_kernel<<<NUM_CODES / 4, 64, 0, stream>>>(cb, esq);
    cvt_swz_kernel<<<NUM_CODES * TILE_K / 256, 256, 0, stream>>>(cb, pbz);
    vq_scan_kernel<<<1024, 128, 0, stream>>>(z, cb, pbz, esq, gwin);
    vq_out_kernel<<<TOTAL_ROWS / ROWS_PER_BLOCK, 256, 0, stream>>>(
        z, cb, gwin, out, loss_acc);
    vq_finalize_kernel<<<1, 1, 0, stream>>>(loss_acc, out);
}